// Round 2
// baseline (220.720 us; speedup 1.0000x reference)
//
#include <hip/hip_runtime.h>
#include <cstdint>

typedef __attribute__((ext_vector_type(4))) float f32x4;
typedef __attribute__((ext_vector_type(8))) short s16x8;

#define LOG2E 1.4426950408889634f

#define B_   4
#define C_   256
#define N_   4096
#define NT_  256    // 16-pixel tiles per batch
#define MB_  128    // 32-key blocks per batch

// workspace byte offsets
#define WS_GATE  0u          // B*N f32            = 65536
#define WS_WFRAG 65536u      // 20*8*4*16*8 bf16   = 163840
#define WS_BIAS  229376u     // 320 f32            = 1280
#define WS_Q     262144u     // B*N*32 bf16        = 1 MiB
#define WS_K     1310720u    // 1 MiB
#define WS_V     2359296u    // B*N*256 bf16       = 8 MiB  (end 10747904)

__device__ __forceinline__ short f2bf(float f) {
  union { float f; unsigned u; } v; v.f = f;
  unsigned u = v.u;
  u += 0x7fffu + ((u >> 16) & 1u);   // RNE
  return (short)(u >> 16);
}

// ---------------- gate: bilinear align-corners 32->64 + sigmoid ----------------
__global__ void gate_kernel(const float* __restrict__ gm, float* __restrict__ gate) {
  int idx = blockIdx.x * 256 + threadIdx.x;        // B*N = 16384
  int b = idx >> 12, n = idx & 4095;
  int y = n >> 6, x = n & 63;
  float fy = (float)(y * 31) / 63.0f;
  float fx = (float)(x * 31) / 63.0f;
  int y0 = (int)fy, x0 = (int)fx;
  float wy = fy - (float)y0, wx = fx - (float)x0;
  int y1 = min(y0 + 1, 31), x1 = min(x0 + 1, 31);
  const float* p = gm + b * 1024;
  float v00 = p[y0 * 32 + x0], v01 = p[y0 * 32 + x1];
  float v10 = p[y1 * 32 + x0], v11 = p[y1 * 32 + x1];
  float top = v00 * (1.f - wx) + v01 * wx;
  float bot = v10 * (1.f - wx) + v11 * wx;
  float gv  = top * (1.f - wy) + bot * wy;
  gate[idx] = 1.0f + 1.0f / (1.0f + expf(-gv));
}

// ---------------- pack W (320x256) into A-frag layout, gather bias ----------------
// frag index d = (((t*8 + ks)*4 + g)*16 + c)*8 + j
//   lane (g,c) elem j holds W[o = t*16 + c][ch = ks*32 + g*8 + j]
__global__ void wprep_kernel(const float* __restrict__ Wq, const float* __restrict__ Wk,
                             const float* __restrict__ Wv, const float* __restrict__ bq,
                             const float* __restrict__ bk, const float* __restrict__ bv,
                             short* __restrict__ wfrag, float* __restrict__ bias) {
  int d0 = blockIdx.x * 256 + threadIdx.x;         // 81920 = 20*8*4*16*8
  int d = d0;
  int j  = d & 7;  d >>= 3;
  int c  = d & 15; d >>= 4;
  int g  = d & 3;  d >>= 2;
  int ks = d & 7;  d >>= 3;
  int t  = d;
  int o  = t * 16 + c;
  int ch = ks * 32 + g * 8 + j;
  float w = (o < 32) ? Wq[o * 256 + ch] : (o < 64) ? Wk[(o - 32) * 256 + ch]
                                                   : Wv[(o - 64) * 256 + ch];
  wfrag[d0] = f2bf(w);
  if (d0 < 320) bias[d0] = (d0 < 32) ? bq[d0] : (d0 < 64) ? bk[d0 - 32] : bv[d0 - 64];
}

// ---------------- fused QKV projection (MFMA) + gate + swizzled bf16 stores ----------------
__global__ __launch_bounds__(256) void proj_kernel(
    const float* __restrict__ x, const short* __restrict__ wfrag,
    const float* __restrict__ bias, const float* __restrict__ gate,
    short* __restrict__ qs, short* __restrict__ ksz, short* __restrict__ vs) {
  int b = blockIdx.x >> 8, nt = blockIdx.x & 255;
  int lane = threadIdx.x & 63, wave = threadIdx.x >> 6;
  int g = lane >> 4, c = lane & 15;
  int n = nt * 16 + c;

  // X B-fragments for all 8 k-steps: lane holds x[b][ks*32+g*8+j][n]
  const float* xb = x + b * (C_ * N_) + n;
  s16x8 xf[8];
  #pragma unroll
  for (int ks = 0; ks < 8; ++ks) {
    int ch0 = ks * 32 + g * 8;
    s16x8 v;
    #pragma unroll
    for (int j = 0; j < 8; ++j) v[j] = f2bf(xb[(ch0 + j) * N_]);
    xf[ks] = v;
  }
  float gt = gate[b * N_ + n];

  for (int t = wave * 5; t < wave * 5 + 5; ++t) {
    f32x4 acc = {0.f, 0.f, 0.f, 0.f};
    #pragma unroll
    for (int ks = 0; ks < 8; ++ks) {
      s16x8 wf = *(const s16x8*)(wfrag + ((((t * 8 + ks) * 4 + g) * 16 + c) * 8));
      acc = __builtin_amdgcn_mfma_f32_16x16x32_bf16(wf, xf[ks], acc, 0, 0, 0);
    }
    #pragma unroll
    for (int jj = 0; jj < 4; ++jj) {
      int o = t * 16 + g * 4 + jj;                 // D row = (lane>>4)*4+reg
      float val = (acc[jj] + bias[o]) * gt;        // D col = lane&15 = pixel
      short bv16 = f2bf(val);
      if (o < 64) {                                 // Q or K: [b][nt][ch>>3][c][ch&7]
        int ch = o & 31;
        short* dst = (o < 32) ? qs : ksz;
        dst[(((b * NT_ + nt) * 4 + (ch >> 3)) * 16 + c) * 8 + (ch & 7)] = bv16;
      } else {                                      // V: [b][mb][ct][g'][c'][j']
        int cv = o - 64;
        int mb = n >> 5, r = n & 31;
        int jp = ((r >> 4) << 2) + (r & 3), gp = (r >> 2) & 3;
        vs[((((b * MB_ + mb) * 16 + (cv >> 4)) * 4 + gp) * 16 + (cv & 15)) * 8 + jp] = bv16;
      }
    }
  }
}

// ---------------- flash attention: S^T = K*Q^T, online softmax, O^T = V*P ----------------
__global__ __launch_bounds__(256) void attn_kernel(
    const short* __restrict__ qs, const short* __restrict__ ksz,
    const short* __restrict__ vs, const float* __restrict__ x,
    const float* __restrict__ gamma, float* __restrict__ out) {
  __shared__ __align__(16) short k_lds[1024];   // 32 keys x 32 ch
  __shared__ __align__(16) short v_lds[8192];   // 32 keys x 256 ch

  int b = blockIdx.x >> 6, qb = blockIdx.x & 63;
  int tid = threadIdx.x;
  int lane = tid & 63, wave = tid >> 6;
  int g = lane >> 4, c = lane & 15;
  int qt = qb * 4 + wave;

  s16x8 qf = *(const s16x8*)(qs + (((b * NT_ + qt) * 4 + g) * 16 + c) * 8);

  f32x4 acc[16];
  #pragma unroll
  for (int i = 0; i < 16; ++i) acc[i] = (f32x4){0.f, 0.f, 0.f, 0.f};
  float m = -3.0e38f, lsum = 0.f;

  for (int mb = 0; mb < MB_; ++mb) {
    { // stage K (2KB) + V (16KB) to LDS
      const float4* vg = (const float4*)(vs + (size_t)(b * MB_ + mb) * 8192);
      float4* vl = (float4*)v_lds;
      #pragma unroll
      for (int i = 0; i < 4; ++i) vl[tid + i * 256] = vg[tid + i * 256];
      if (tid < 128)
        ((float4*)k_lds)[tid] = ((const float4*)(ksz + (size_t)(b * MB_ + mb) * 1024))[tid];
    }
    __syncthreads();

    s16x8 kf0 = *(const s16x8*)(k_lds + ((0 * 4 + g) * 16 + c) * 8);
    s16x8 kf1 = *(const s16x8*)(k_lds + ((1 * 4 + g) * 16 + c) * 8);
    f32x4 z = {0.f, 0.f, 0.f, 0.f};
    f32x4 st0 = __builtin_amdgcn_mfma_f32_16x16x32_bf16(kf0, qf, z, 0, 0, 0);
    f32x4 st1 = __builtin_amdgcn_mfma_f32_16x16x32_bf16(kf1, qf, z, 0, 0, 0);

    float s[8];
    s[0] = st0[0]; s[1] = st0[1]; s[2] = st0[2]; s[3] = st0[3];
    s[4] = st1[0]; s[5] = st1[1]; s[6] = st1[2]; s[7] = st1[3];
    float pm = s[0];
    #pragma unroll
    for (int j = 1; j < 8; ++j) pm = fmaxf(pm, s[j]);
    pm = fmaxf(pm, __shfl_xor(pm, 16));
    pm = fmaxf(pm, __shfl_xor(pm, 32));
    float mnew = fmaxf(m, pm);
    float scale = exp2f((m - mnew) * LOG2E);

    float psum = 0.f;
    s16x8 pf;
    #pragma unroll
    for (int j = 0; j < 8; ++j) {
      float p = exp2f((s[j] - mnew) * LOG2E);
      psum += p;
      pf[j] = f2bf(p);
    }
    psum += __shfl_xor(psum, 16);
    psum += __shfl_xor(psum, 32);
    lsum = lsum * scale + psum;
    m = mnew;

    #pragma unroll
    for (int i = 0; i < 16; ++i) {
      acc[i][0] *= scale; acc[i][1] *= scale;
      acc[i][2] *= scale; acc[i][3] *= scale;
    }

    #pragma unroll
    for (int ct = 0; ct < 16; ++ct) {
      s16x8 vf = *(const s16x8*)(v_lds + ((ct * 4 + g) * 16 + c) * 8);
      acc[ct] = __builtin_amdgcn_mfma_f32_16x16x32_bf16(vf, pf, acc[ct], 0, 0, 0);
    }
    __syncthreads();
  }

  float gmm = gamma[0];
  float rn = 1.0f / lsum;                 // lane-local: q = lane&15
  int n = qt * 16 + c;
  #pragma unroll
  for (int ct = 0; ct < 16; ++ct) {
    #pragma unroll
    for (int jj = 0; jj < 4; ++jj) {
      int cc = ct * 16 + g * 4 + jj;      // O^T row = channel
      int idx = (b * C_ + cc) * N_ + n;
      out[idx] = gmm * acc[ct][jj] * rn + x[idx];
    }
  }
}

extern "C" void kernel_launch(void* const* d_in, const int* in_sizes, int n_in,
                              void* d_out, int out_size, void* d_ws, size_t ws_size,
                              hipStream_t stream) {
  const float* x     = (const float*)d_in[0];
  const float* gm    = (const float*)d_in[1];
  const float* Wq    = (const float*)d_in[2];
  const float* bq    = (const float*)d_in[3];
  const float* Wk    = (const float*)d_in[4];
  const float* bk    = (const float*)d_in[5];
  const float* Wv    = (const float*)d_in[6];
  const float* bv    = (const float*)d_in[7];
  const float* gamma = (const float*)d_in[8];

  char*  ws    = (char*)d_ws;          // needs ~10.3 MB
  float* gate  = (float*)(ws + WS_GATE);
  short* wfrag = (short*)(ws + WS_WFRAG);
  float* bias  = (float*)(ws + WS_BIAS);
  short* qs    = (short*)(ws + WS_Q);
  short* ksz   = (short*)(ws + WS_K);
  short* vs    = (short*)(ws + WS_V);
  float* out   = (float*)d_out;

  gate_kernel<<<dim3(64), dim3(256), 0, stream>>>(gm, gate);
  wprep_kernel<<<dim3(320), dim3(256), 0, stream>>>(Wq, Wk, Wv, bq, bk, bv, wfrag, bias);
  proj_kernel<<<dim3(1024), dim3(256), 0, stream>>>(x, wfrag, bias, gate, qs, ksz, vs);
  attn_kernel<<<dim3(256), dim3(256), 0, stream>>>(qs, ksz, vs, x, gamma, out);
}

// Round 3
// 133.303 us; speedup vs baseline: 1.6558x; 1.6558x over previous
//
#include <hip/hip_runtime.h>
#include <cstdint>

typedef __attribute__((ext_vector_type(4))) float f32x4;
typedef __attribute__((ext_vector_type(8))) short s16x8;

#define LOG2E 1.4426950408889634f

#define B_   4
#define C_   256
#define N_   4096
#define NT_  256    // 16-pixel tiles per batch
#define MB_  128    // 32-key blocks per batch

// workspace byte offsets
#define WS_GATE  0u          // B*N f32            = 65536
#define WS_WFRAG 65536u      // 20*8*4*16*8 bf16   = 163840
#define WS_BIAS  229376u     // 320 f32            = 1280
#define WS_Q     262144u     // B*N*32 bf16        = 1 MiB
#define WS_K     1310720u    // 1 MiB
#define WS_V     2359296u    // B*N*256 bf16       = 8 MiB  (end 10747904)

__device__ __forceinline__ short f2bf(float f) {
  union { float f; unsigned u; } v; v.f = f;
  unsigned u = v.u;
  u += 0x7fffu + ((u >> 16) & 1u);   // RNE
  return (short)(u >> 16);
}

// ---------------- gate: bilinear align-corners 32->64 + sigmoid ----------------
__global__ void gate_kernel(const float* __restrict__ gm, float* __restrict__ gate) {
  int idx = blockIdx.x * 256 + threadIdx.x;        // B*N = 16384
  int b = idx >> 12, n = idx & 4095;
  int y = n >> 6, x = n & 63;
  float fy = (float)(y * 31) / 63.0f;
  float fx = (float)(x * 31) / 63.0f;
  int y0 = (int)fy, x0 = (int)fx;
  float wy = fy - (float)y0, wx = fx - (float)x0;
  int y1 = min(y0 + 1, 31), x1 = min(x0 + 1, 31);
  const float* p = gm + b * 1024;
  float v00 = p[y0 * 32 + x0], v01 = p[y0 * 32 + x1];
  float v10 = p[y1 * 32 + x0], v11 = p[y1 * 32 + x1];
  float top = v00 * (1.f - wx) + v01 * wx;
  float bot = v10 * (1.f - wx) + v11 * wx;
  float gv  = top * (1.f - wy) + bot * wy;
  gate[idx] = 1.0f + 1.0f / (1.0f + expf(-gv));
}

// ---------------- pack W (320x256) into A-frag layout, gather bias ----------------
// frag index d = (((t*8 + ks)*4 + g)*16 + c)*8 + j
//   lane (g,c) elem j holds W[o = t*16 + c][ch = ks*32 + g*8 + j]
__global__ void wprep_kernel(const float* __restrict__ Wq, const float* __restrict__ Wk,
                             const float* __restrict__ Wv, const float* __restrict__ bq,
                             const float* __restrict__ bk, const float* __restrict__ bv,
                             short* __restrict__ wfrag, float* __restrict__ bias) {
  int d0 = blockIdx.x * 256 + threadIdx.x;         // 81920 = 20*8*4*16*8
  int d = d0;
  int j  = d & 7;  d >>= 3;
  int c  = d & 15; d >>= 4;
  int g  = d & 3;  d >>= 2;
  int ks = d & 7;  d >>= 3;
  int t  = d;
  int o  = t * 16 + c;
  int ch = ks * 32 + g * 8 + j;
  float w = (o < 32) ? Wq[o * 256 + ch] : (o < 64) ? Wk[(o - 32) * 256 + ch]
                                                   : Wv[(o - 64) * 256 + ch];
  wfrag[d0] = f2bf(w);
  if (d0 < 320) bias[d0] = (d0 < 32) ? bq[d0] : (d0 < 64) ? bk[d0 - 32] : bv[d0 - 64];
}

// ---------------- fused QKV projection (MFMA) + gate + swizzled bf16 stores ----------------
__global__ __launch_bounds__(256) void proj_kernel(
    const float* __restrict__ x, const short* __restrict__ wfrag,
    const float* __restrict__ bias, const float* __restrict__ gate,
    short* __restrict__ qs, short* __restrict__ ksz, short* __restrict__ vs) {
  int b = blockIdx.x >> 8, nt = blockIdx.x & 255;
  int lane = threadIdx.x & 63, wave = threadIdx.x >> 6;
  int g = lane >> 4, c = lane & 15;
  int n = nt * 16 + c;

  // X B-fragments for all 8 k-steps: lane holds x[b][ks*32+g*8+j][n]
  const float* xb = x + b * (C_ * N_) + n;
  s16x8 xf[8];
  #pragma unroll
  for (int ks = 0; ks < 8; ++ks) {
    int ch0 = ks * 32 + g * 8;
    s16x8 v;
    #pragma unroll
    for (int j = 0; j < 8; ++j) v[j] = f2bf(xb[(ch0 + j) * N_]);
    xf[ks] = v;
  }
  float gt = gate[b * N_ + n];

  for (int t = wave * 5; t < wave * 5 + 5; ++t) {
    f32x4 acc = {0.f, 0.f, 0.f, 0.f};
    #pragma unroll
    for (int ks = 0; ks < 8; ++ks) {
      s16x8 wf = *(const s16x8*)(wfrag + ((((t * 8 + ks) * 4 + g) * 16 + c) * 8));
      acc = __builtin_amdgcn_mfma_f32_16x16x32_bf16(wf, xf[ks], acc, 0, 0, 0);
    }
    #pragma unroll
    for (int jj = 0; jj < 4; ++jj) {
      int o = t * 16 + g * 4 + jj;                 // D row = (lane>>4)*4+reg
      float val = (acc[jj] + bias[o]) * gt;        // D col = lane&15 = pixel
      short bv16 = f2bf(val);
      if (o < 64) {                                 // Q or K: [b][nt][ch>>3][c][ch&7]
        int ch = o & 31;
        short* dst = (o < 32) ? qs : ksz;
        dst[(((b * NT_ + nt) * 4 + (ch >> 3)) * 16 + c) * 8 + (ch & 7)] = bv16;
      } else {                                      // V: [b][mb][ct][g'][c'][j']
        int cv = o - 64;
        int mb = n >> 5, r = n & 31;
        int jp = ((r >> 4) << 2) + (r & 3), gp = (r >> 2) & 3;
        vs[((((b * MB_ + mb) * 16 + (cv >> 4)) * 4 + gp) * 16 + (cv & 15)) * 8 + jp] = bv16;
      }
    }
  }
}

// ---------------- flash attention, split-KV within block ----------------
// 1024 blocks, 4 waves each. Block owns one 16-query tile; wave w processes
// kv-blocks mb = w + 4*i (32 iters), private (m,l,acc). No K/V LDS staging:
// fragment-linear K/V stream from L2 (per-XCD working set pinned by decode).
// End: cross-wave combine via LDS.
__global__ __launch_bounds__(256) void attn_kernel(
    const short* __restrict__ qs, const short* __restrict__ ksz,
    const short* __restrict__ vs, const float* __restrict__ x,
    const float* __restrict__ gamma, float* __restrict__ out) {
  __shared__ float comb_m[4][64];
  __shared__ float comb_l[4][64];
  __shared__ __align__(16) float sumbuf[4][4][64][4];   // 16 KB

  int bid = blockIdx.x;
  // XCD-aware decode: XCD = bid%8 (empirical round-robin); batch b -> XCDs {2b,2b+1}
  int b  = (bid & 7) >> 1;
  int qt = ((bid >> 3) << 1) | (bid & 1);               // 0..255
  int tid = threadIdx.x;
  int lane = tid & 63, wave = tid >> 6;
  int g = lane >> 4, c = lane & 15;

  s16x8 qf = *(const s16x8*)(qs + (((b * NT_ + qt) * 4 + g) * 16 + c) * 8);

  f32x4 acc[16];
  #pragma unroll
  for (int i = 0; i < 16; ++i) acc[i] = (f32x4){0.f, 0.f, 0.f, 0.f};
  float m = -3.0e38f, lsum = 0.f;

  const short* kb0 = ksz + (size_t)b * (MB_ * 1024) + ((g * 16 + c) * 8);
  const short* vb0 = vs  + (size_t)b * (MB_ * 8192) + ((g * 16 + c) * 8);

  for (int i = 0; i < 32; ++i) {
    int mb = wave + i * 4;
    const short* kb = kb0 + mb * 1024;
    const short* vb = vb0 + mb * 8192;

    s16x8 kf0 = *(const s16x8*)(kb);
    s16x8 kf1 = *(const s16x8*)(kb + 512);          // ks=1: +4*16*8
    f32x4 z = {0.f, 0.f, 0.f, 0.f};
    f32x4 st0 = __builtin_amdgcn_mfma_f32_16x16x32_bf16(kf0, qf, z, 0, 0, 0);
    f32x4 st1 = __builtin_amdgcn_mfma_f32_16x16x32_bf16(kf1, qf, z, 0, 0, 0);

    float s[8];
    s[0] = st0[0]; s[1] = st0[1]; s[2] = st0[2]; s[3] = st0[3];
    s[4] = st1[0]; s[5] = st1[1]; s[6] = st1[2]; s[7] = st1[3];
    float pm = fmaxf(fmaxf(fmaxf(s[0], s[1]), fmaxf(s[2], s[3])),
                     fmaxf(fmaxf(s[4], s[5]), fmaxf(s[6], s[7])));
    pm = fmaxf(pm, __shfl_xor(pm, 16));
    pm = fmaxf(pm, __shfl_xor(pm, 32));
    float mnew = fmaxf(m, pm);
    float scale = exp2f((m - mnew) * LOG2E);

    float psum = 0.f;
    s16x8 pf;
    #pragma unroll
    for (int j = 0; j < 8; ++j) {
      float p = exp2f((s[j] - mnew) * LOG2E);
      psum += p;
      pf[j] = f2bf(p);
    }
    psum += __shfl_xor(psum, 16);
    psum += __shfl_xor(psum, 32);
    lsum = lsum * scale + psum;
    m = mnew;

    #pragma unroll
    for (int ii = 0; ii < 16; ++ii) {
      acc[ii][0] *= scale; acc[ii][1] *= scale;
      acc[ii][2] *= scale; acc[ii][3] *= scale;
    }

    #pragma unroll
    for (int ct = 0; ct < 16; ++ct) {
      s16x8 vf = *(const s16x8*)(vb + ct * 512);
      acc[ct] = __builtin_amdgcn_mfma_f32_16x16x32_bf16(vf, pf, acc[ct], 0, 0, 0);
    }
  }

  // ---- cross-wave combine ----
  comb_m[wave][lane] = m;
  comb_l[wave][lane] = lsum;
  __syncthreads();
  float M = fmaxf(fmaxf(comb_m[0][lane], comb_m[1][lane]),
                  fmaxf(comb_m[2][lane], comb_m[3][lane]));
  float L = 0.f;
  #pragma unroll
  for (int w2 = 0; w2 < 4; ++w2)
    L += comb_l[w2][lane] * exp2f((comb_m[w2][lane] - M) * LOG2E);
  float myscale = exp2f((m - M) * LOG2E);
  float rn = gamma[0] / L;
  int n = qt * 16 + c;

  for (int chunk = 0; chunk < 4; ++chunk) {
    #pragma unroll
    for (int q = 0; q < 4; ++q) {
      int ct = chunk * 4 + q;
      f32x4 a = acc[ct];
      a[0] *= myscale; a[1] *= myscale; a[2] *= myscale; a[3] *= myscale;
      *(f32x4*)&sumbuf[wave][q][lane][0] = a;
    }
    __syncthreads();
    f32x4 ssum = *(const f32x4*)&sumbuf[0][wave][lane][0];
    #pragma unroll
    for (int w2 = 1; w2 < 4; ++w2) {
      f32x4 t2 = *(const f32x4*)&sumbuf[w2][wave][lane][0];
      ssum[0] += t2[0]; ssum[1] += t2[1]; ssum[2] += t2[2]; ssum[3] += t2[3];
    }
    int ct = chunk * 4 + wave;
    #pragma unroll
    for (int jj = 0; jj < 4; ++jj) {
      int cc = ct * 16 + g * 4 + jj;
      int idx = (b * C_ + cc) * N_ + n;
      out[idx] = rn * ssum[jj] + x[idx];
    }
    __syncthreads();
  }
}

extern "C" void kernel_launch(void* const* d_in, const int* in_sizes, int n_in,
                              void* d_out, int out_size, void* d_ws, size_t ws_size,
                              hipStream_t stream) {
  const float* x     = (const float*)d_in[0];
  const float* gm    = (const float*)d_in[1];
  const float* Wq    = (const float*)d_in[2];
  const float* bq    = (const float*)d_in[3];
  const float* Wk    = (const float*)d_in[4];
  const float* bk    = (const float*)d_in[5];
  const float* Wv    = (const float*)d_in[6];
  const float* bv    = (const float*)d_in[7];
  const float* gamma = (const float*)d_in[8];

  char*  ws    = (char*)d_ws;          // needs ~10.3 MB
  float* gate  = (float*)(ws + WS_GATE);
  short* wfrag = (short*)(ws + WS_WFRAG);
  float* bias  = (float*)(ws + WS_BIAS);
  short* qs    = (short*)(ws + WS_Q);
  short* ksz   = (short*)(ws + WS_K);
  short* vs    = (short*)(ws + WS_V);
  float* out   = (float*)d_out;

  gate_kernel<<<dim3(64), dim3(256), 0, stream>>>(gm, gate);
  wprep_kernel<<<dim3(320), dim3(256), 0, stream>>>(Wq, Wk, Wv, bq, bk, bv, wfrag, bias);
  proj_kernel<<<dim3(1024), dim3(256), 0, stream>>>(x, wfrag, bias, gate, qs, ksz, vs);
  attn_kernel<<<dim3(1024), dim3(256), 0, stream>>>(qs, ksz, vs, x, gamma, out);
}